// Round 1
// baseline (439.158 us; speedup 1.0000x reference)
//
#include <hip/hip_runtime.h>
#include <stdint.h>

#define FDIM 8192
#define KSEL 512
#define NT   512
#define EPT  (FDIM / NT / 4)   // 4 float4s = 16 scalar elements per thread
#define NBIN 4096
#define NWAVE (NT / 64)

// Order-preserving float -> uint key (larger key <=> larger float)
__device__ __forceinline__ unsigned keyOf(unsigned u) {
    return (u & 0x80000000u) ? ~u : (u | 0x80000000u);
}
__device__ __forceinline__ float valOf(unsigned key) {
    unsigned u = (key & 0x80000000u) ? (key ^ 0x80000000u) : ~key;
    return __uint_as_float(u);
}

__global__ __launch_bounds__(NT) void topk_mask_kernel(const float* __restrict__ x,
                                                       float* __restrict__ out) {
    // hist as uint4 so scan/zero phases use ds_read_b128/ds_write_b128:
    // scalar hist[8t+i] reads put 64 lanes on 4 banks (16-way conflict, ~33cyc/op);
    // one b128 covers 32B/lane -> wave footprint spans all 32 banks uniformly.
    __shared__ uint4 hist4[NBIN / 4];      // 16 KiB: 12-bit-digit histogram
    unsigned* hist = (unsigned*)hist4;
    __shared__ unsigned wtot[NWAVE];
    __shared__ unsigned s_prefix, s_need, s_sub, s_tiecnt;
    __shared__ unsigned tiebuf[64];

    const int row  = blockIdx.x;
    const int t    = threadIdx.x;
    const int lane = t & 63;
    const int wave = t >> 6;

    const float4* xrow = (const float4*)(x + (size_t)row * FDIM);
    float4*       orow = (float4*)(out + (size_t)row * FDIM);

    // ---- Load row into registers as order-preserving keys (coalesced float4) ----
    uint4 kreg[EPT];
    #pragma unroll
    for (int j = 0; j < EPT; ++j) {
        float4 v = xrow[j * NT + t];
        kreg[j].x = keyOf(__float_as_uint(v.x));
        kreg[j].y = keyOf(__float_as_uint(v.y));
        kreg[j].z = keyOf(__float_as_uint(v.z));
        kreg[j].w = keyOf(__float_as_uint(v.w));
    }
    #pragma unroll
    for (int i = t; i < NBIN / 4; i += NT) hist4[i] = make_uint4(0u, 0u, 0u, 0u);
    if (t == 0) { s_prefix = 0u; s_need = KSEL; s_tiecnt = 0u; }
    __syncthreads();

    // ---- Radix select, 3 rounds of 12/12/8 bits. Counting on the DS pipe:
    //      4096 bins spread normal-data digits so same-address multiplicity ~2 (free).
    #pragma unroll
    for (int round = 0; round < 3; ++round) {
        const unsigned pref = s_prefix;   // block-uniform, stable until end-of-round
        const unsigned need = s_need;

        if (round == 0) {
            #pragma unroll
            for (int j = 0; j < EPT; ++j) {
                #pragma unroll
                for (int c = 0; c < 4; ++c) {
                    unsigned key = (&kreg[j].x)[c];
                    atomicAdd(&hist[key >> 20], 1u);
                }
            }
        } else if (round == 1) {
            #pragma unroll
            for (int j = 0; j < EPT; ++j) {
                #pragma unroll
                for (int c = 0; c < 4; ++c) {
                    unsigned key = (&kreg[j].x)[c];
                    if ((key >> 20) == pref)                       // ~290 of 8192 match
                        atomicAdd(&hist[(key >> 8) & 0xFFFu], 1u);
                }
            }
        } else {
            #pragma unroll
            for (int j = 0; j < EPT; ++j) {
                #pragma unroll
                for (int c = 0; c < 4; ++c) {
                    unsigned key = (&kreg[j].x)[c];
                    if ((key >> 8) == pref)                        // ~1-3 match
                        atomicAdd(&hist[key & 0xFFu], 1u);
                }
            }
        }
        __syncthreads();

        // ---- Hierarchical suffix-scan of 4096 bins: 8 bins/thread via two
        //      ds_read_b128 (conflict-free in aggregate) -> wave shfl scan ->
        //      8 wave partials. Zero own bins with two ds_write_b128.
        const unsigned b4 = (unsigned)t * 2u;      // two uint4 per thread
        const uint4 h0 = hist4[b4];
        const uint4 h1 = hist4[b4 + 1];
        unsigned sfx[9];                   // sfx[i] = sum of own bins [i..7]
        sfx[8] = 0u;
        sfx[7] = h1.w;
        sfx[6] = sfx[7] + h1.z;
        sfx[5] = sfx[6] + h1.y;
        sfx[4] = sfx[5] + h1.x;
        sfx[3] = sfx[4] + h0.w;
        sfx[2] = sfx[3] + h0.z;
        sfx[1] = sfx[2] + h0.y;
        sfx[0] = sfx[1] + h0.x;
        hist4[b4]     = make_uint4(0u, 0u, 0u, 0u);   // ready for next round
        hist4[b4 + 1] = make_uint4(0u, 0u, 0u, 0u);
        const unsigned tot = sfx[0];
        unsigned incl = tot;               // inclusive suffix over lanes >= this lane
        #pragma unroll
        for (int off = 1; off < 64; off <<= 1) {
            unsigned y = __shfl_down(incl, off);
            incl += (lane + off < 64) ? y : 0u;
        }
        if (lane == 0) wtot[wave] = incl;  // wave total
        __syncthreads();
        unsigned gb = incl - tot;          // beyond-this-thread within wave
        #pragma unroll
        for (int w = 0; w < NWAVE; ++w) gb += (w > wave) ? wtot[w] : 0u;

        // exactly one (thread, i) satisfies the straddle condition
        const unsigned base = (unsigned)t * (NBIN / NT);
        #pragma unroll
        for (int i = 0; i < 8; ++i) {
            unsigned S = gb + sfx[i];                  // count with digit >= base+i
            unsigned h = sfx[i] - sfx[i + 1];
            if (S >= need && S - h < need) {
                s_prefix = (round == 2) ? ((pref << 8) | (base + (unsigned)i))
                                        : ((pref << 12) | (base + (unsigned)i));
                s_need = need - (S - h);
                s_sub  = h;
            }
        }
        __syncthreads();
    }

    const unsigned thresh = s_prefix;   // exact key of the KSEL-th largest
    const unsigned keepEq = s_need;     // # threshold-equal elements to keep
    const unsigned eqCnt  = s_sub;      // total threshold-equal elements
    const bool simple = (eqCnt == keepEq);

    // ---- Output pass straight from registers (coalesced float4 stores) ----
    if (simple) {
        #pragma unroll
        for (int j = 0; j < EPT; ++j) {
            uint4 k = kreg[j];
            float4 o;
            o.x = (k.x >= thresh) ? valOf(k.x) : 0.0f;
            o.y = (k.y >= thresh) ? valOf(k.y) : 0.0f;
            o.z = (k.z >= thresh) ? valOf(k.z) : 0.0f;
            o.w = (k.w >= thresh) ? valOf(k.w) : 0.0f;
            orow[j * NT + t] = o;
        }
    } else {
        #pragma unroll
        for (int j = 0; j < EPT; ++j) {
            uint4 k = kreg[j];
            float4 o;
            o.x = (k.x > thresh) ? valOf(k.x) : 0.0f;
            o.y = (k.y > thresh) ? valOf(k.y) : 0.0f;
            o.z = (k.z > thresh) ? valOf(k.z) : 0.0f;
            o.w = (k.w > thresh) ? valOf(k.w) : 0.0f;
            orow[j * NT + t] = o;
        }
        // ---- Rare tie path: stable (lowest-index) selection among equals ----
        #pragma unroll
        for (int j = 0; j < EPT; ++j) {
            #pragma unroll
            for (int c = 0; c < 4; ++c) {
                unsigned key = (&kreg[j].x)[c];
                if (key == thresh) {
                    unsigned slot = atomicAdd(&s_tiecnt, 1u);
                    if (slot < 64u) tiebuf[slot] = 4u * (unsigned)(j * NT + t) + (unsigned)c;
                }
            }
        }
        __syncthreads();
        if (t == 0) {
            const unsigned m = s_tiecnt;
            const float v = valOf(thresh);
            if (m <= 64u) {
                for (unsigned i = 0; i < m; ++i) {
                    unsigned idx = tiebuf[i], rank = 0;
                    for (unsigned q = 0; q < m; ++q) rank += (tiebuf[q] < idx);
                    if (rank < keepEq) out[(size_t)row * FDIM + idx] = v;
                }
            } else {
                unsigned c = 0;
                for (int i = 0; i < FDIM && c < keepEq; ++i) {
                    if (keyOf(__float_as_uint(x[(size_t)row * FDIM + i])) == thresh) {
                        out[(size_t)row * FDIM + i] = v; ++c;
                    }
                }
            }
        }
    }
}

extern "C" void kernel_launch(void* const* d_in, const int* in_sizes, int n_in,
                              void* d_out, int out_size, void* d_ws, size_t ws_size,
                              hipStream_t stream) {
    const float* x = (const float*)d_in[0];
    float* out = (float*)d_out;
    topk_mask_kernel<<<dim3(FDIM), dim3(NT), 0, stream>>>(x, out);
}